// Round 4
// baseline (109.110 us; speedup 1.0000x reference)
//
#include <hip/hip_runtime.h>

#define BB 4
#define NN 16384
#define MM 8192      // N/2
#define FD 64
#define CHUNK 1024   // candidates staged per LDS tile
#define QPB 256      // queries per block == threads per block

// d_out float offsets (outputs concatenated flat in return order)
#define OUT0 0              // valid_pc   (4,8192,3)  = 98304
#define OUT1 98304          // valid_feats(4,8192,64) = 2097152
#define OUT2 2195456        // n_idx      (4,8192)    = 32768
#define OUT3 2228224        // rnds       (1,16384)   = 16384

struct Partial { float m1, m2; int i1, i2; };  // 16B

// XLA:CPU multiply->reduce fusion (no contraction): rounded squares, sequential adds.
__device__ __forceinline__ float sumsq3_rn(float x, float y, float z) {
  return __fadd_rn(__fadd_rn(__fmul_rn(x, x), __fmul_rn(y, y)), __fmul_rn(z, z));
}

// XLA:CPU f32 gemm micro-kernel (K ascending, acc init 0):
// acc = fma(k2, fma(k1, rn(k0)))
__device__ __forceinline__ float dot3_gemm(float ax, float ay, float az,
                                           float bx, float by, float bz) {
  return __fmaf_rn(az, bz, __fmaf_rn(ay, by, __fmul_rn(ax, bx)));
}

__global__ __launch_bounds__(256) void gather_kernel(
    const float* __restrict__ pc, const float* __restrict__ feats,
    const int* __restrict__ perm, float* __restrict__ out) {
  int idx = blockIdx.x * 256 + threadIdx.x;
  const int FEATS_TOT = BB * MM * FD;          // 2097152
  const int PC_TOT    = BB * MM * 3;           // 98304
  if (idx < FEATS_TOT) {
    int f = idx & 63;
    int r = (idx >> 6) & (MM - 1);
    int b = idx >> 19;                          // / (MM*FD)
    int vi = perm[r];
    out[OUT1 + idx] = feats[((b * NN + vi) << 6) + f];
  } else if (idx < FEATS_TOT + PC_TOT) {
    int k = idx - FEATS_TOT;
    int d = k % 3;
    int r = (k / 3) & (MM - 1);
    int b = k / (MM * 3);
    int vi = perm[r];
    out[OUT0 + k] = pc[(b * NN + vi) * 3 + d];
  } else if (idx < FEATS_TOT + PC_TOT + NN) {
    int k = idx - FEATS_TOT - PC_TOT;
    out[OUT3 + k] = (float)perm[k];
  }
}

// Each block: 256 queries x (MM/nchunk) candidates (staged in LDS tiles).
// nchunk>1: per-chunk top-2 partials to `part`; nchunk==1: final index to out.
__global__ __launch_bounds__(256) void knn_kernel(
    const float* __restrict__ pc, const int* __restrict__ perm,
    Partial* __restrict__ part, float* __restrict__ out, int nchunk) {
  #pragma clang fp contract(off)
  int blk = blockIdx.x;
  int c  = blk % nchunk;          // chunk id
  int qb = blk / nchunk;          // query-block id
  int q  = qb * QPB + threadIdx.x;   // global query 0..B*M-1
  int b  = q >> 13;               // / MM
  int j  = q & (MM - 1);
  int qi = perm[MM + j];          // invalid point index
  const float* qp = pc + (b * NN + qi) * 3;
  float qx = qp[0], qy = qp[1], qz = qp[2];
  float q2 = sumsq3_rn(qx, qy, qz);

  __shared__ float4 tile[CHUNK];   // (x, y, z, p2)

  int span = MM / nchunk;
  int begin = c * span, end = begin + span;

  float m1 = 3.4e38f, m2 = 3.4e38f;
  int i1 = 0, i2 = 0;

  for (int t0 = begin; t0 < end; t0 += CHUNK) {
    __syncthreads();
    for (int k = threadIdx.x; k < CHUNK; k += 256) {
      int p = t0 + k;
      int vi = perm[p];
      const float* pp = pc + (b * NN + vi) * 3;
      float px = pp[0], py = pp[1], pz = pp[2];
      tile[k] = make_float4(px, py, pz, sumsq3_rn(px, py, pz));
    }
    __syncthreads();
    #pragma unroll 4
    for (int k = 0; k < CHUNK; ++k) {
      float4 t = tile[k];
      // gemm-style FMA chain for the cross term
      float cross = dot3_gemm(qx, qy, qz, t.x, t.y, t.z);
      // d2 = rn(rn(q2 - 2*cross) + p2); 2*cross exact
      float d2 = __fadd_rn(__fsub_rn(q2, __fmul_rn(2.0f, cross)), t.w);
      if (d2 < m2) {
        if (d2 < m1) { m2 = m1; i2 = i1; m1 = d2; i1 = t0 + k; }
        else         { m2 = d2; i2 = t0 + k; }
      }
    }
  }

  if (part != nullptr) {
    Partial pr; pr.m1 = m1; pr.m2 = m2; pr.i1 = i1; pr.i2 = i2;
    part[q * nchunk + c] = pr;
  } else {
    out[OUT2 + q] = (float)i2;
  }
}

__global__ __launch_bounds__(256) void knn_merge_kernel(
    const Partial* __restrict__ part, float* __restrict__ out, int nchunk) {
  int q = blockIdx.x * 256 + threadIdx.x;   // 0..B*M-1
  float m1 = 3.4e38f, m2 = 3.4e38f;
  int i1 = 0, i2 = 0;
  for (int c = 0; c < nchunk; ++c) {
    Partial p = part[q * nchunk + c];
    // ascending chunk order = ascending candidate-index ranges, so strict <
    // preserves top_k's stable lowest-index-first tie semantics.
    if (p.m1 < m1)      { m2 = m1; i2 = i1; m1 = p.m1; i1 = p.i1; }
    else if (p.m1 < m2) { m2 = p.m1; i2 = p.i1; }
    if (p.m2 < m1)      { m2 = m1; i2 = i1; m1 = p.m2; i1 = p.i2; }
    else if (p.m2 < m2) { m2 = p.m2; i2 = p.i2; }
  }
  out[OUT2 + q] = (float)i2;
}

extern "C" void kernel_launch(void* const* d_in, const int* in_sizes, int n_in,
                              void* d_out, int out_size, void* d_ws, size_t ws_size,
                              hipStream_t stream) {
  const float* pc    = (const float*)d_in[0];
  const float* feats = (const float*)d_in[1];
  const int*   perm  = (const int*)d_in[2];
  float* out = (float*)d_out;

  // Gather: 2097152 + 98304 + 16384 = 2211840 elements -> 8640 blocks of 256
  gather_kernel<<<8640, 256, 0, stream>>>(pc, feats, perm, out);

  // Pick the largest chunk split whose partials fit in d_ws.
  int nchunk = 1;
  if      (ws_size >= (size_t)BB * MM * 8 * sizeof(Partial)) nchunk = 8;
  else if (ws_size >= (size_t)BB * MM * 4 * sizeof(Partial)) nchunk = 4;
  else if (ws_size >= (size_t)BB * MM * 2 * sizeof(Partial)) nchunk = 2;

  if (nchunk > 1) {
    Partial* part = (Partial*)d_ws;
    knn_kernel<<<(BB * MM / QPB) * nchunk, 256, 0, stream>>>(pc, perm, part, out, nchunk);
    knn_merge_kernel<<<BB * MM / 256, 256, 0, stream>>>(part, out, nchunk);
  } else {
    knn_kernel<<<BB * MM / QPB, 256, 0, stream>>>(pc, perm, nullptr, out, 1);
  }
}